// Round 16
// baseline (38.635 us; speedup 1.0000x reference)
//
#include <hip/hip_runtime.h>
#include <hip/hip_bf16.h>

// Sliding-window block-causal attention — paired-block staging, 1 barrier / 2 blocks.
// B=2 H=8 S=4096 D=64, BLK=32, W=16. f32 I/O, bf16 MFMA, f32 softmax.
// WG = 256 thr = 4 waves, wave w owns q-block n0+w. Union window (19 blocks)
// staged as 10 aligned PAIRS, double-buffered; issue-early / write-late.
// In-register swapped softmax + defer-max (v11/v14-verified core). 512 WGs.

#define NH    8
#define SEQ   4096
#define DIM   64
#define NBLK  128
#define WIN   16
#define QG    4
#define GROUPS (NBLK / QG)   // 32

typedef __bf16 bf16x8 __attribute__((ext_vector_type(8)));
typedef __bf16 bf16x4 __attribute__((ext_vector_type(4)));
typedef float  f32x4  __attribute__((ext_vector_type(4)));
typedef unsigned short u16;
typedef unsigned int   u32;

#define KSTR 72   // Kt row stride (u16): 144B rows, 16B-aligned
#define VSTR 40   // Vt row stride (u16): 80B rows, 8B-aligned
#define DTHR 8.0f

__device__ __forceinline__ bf16x8 cvt8(f32x4 a, f32x4 b) {
    bf16x8 r;
#pragma unroll
    for (int j = 0; j < 4; ++j) { r[j] = (__bf16)a[j]; r[4 + j] = (__bf16)b[j]; }
    return r;
}

__global__ __launch_bounds__(256)
void sparse_attn_v15(const float* __restrict__ Q,
                     const float* __restrict__ K,
                     const float* __restrict__ V,
                     float* __restrict__ O)
{
    // XCD-chunked bijective swizzle (512 WGs % 8 == 0)
    const int b  = (int)blockIdx.x;
    const int lg = (b & 7) * 64 + (b >> 3);
    const int bh = lg >> 5;              // 0..15
    const int n0 = (lg & 31) * QG;       // group's first q-block

    const int t    = (int)threadIdx.x;
    const int wave = t >> 6;             // 0..3, owns q-block n0+wave
    const int lane = t & 63;
    const int l15  = lane & 15;
    const int l4   = lane >> 4;          // 0..3
    const int nq   = n0 + wave;

    __shared__ u16 Kt[2][2][32][KSTR];   // [buf][sub][row][d]   18.4 KB
    __shared__ u16 Vt[2][2][64][VSTR];   // [buf][sub][d][key]   20.5 KB

    const size_t base = (size_t)bh * SEQ * DIM;
    const float SC = 0.125f * 1.44269504088896340736f;  // d^-0.5 * log2(e)

    // staging coords
    const int skrow = t >> 3;            // K row 0..31
    const int skc   = (t & 7) * 8;       // K d-chunk
    const int svkey = (t & 15) * 2;      // V key pair
    const int svdg  = t >> 4;            // V d-group 0..15

    // ---- Q fragments, pre-scaled (verified v11) ----
    bf16x8 qf[2][2];
#pragma unroll
    for (int rt = 0; rt < 2; ++rt) {
        const float* qp = Q + base + (size_t)(nq * 32 + rt * 16 + l15) * DIM + l4 * 8;
        f32x4 a0 = *(const f32x4*)qp        * SC;
        f32x4 b0 = *(const f32x4*)(qp + 4)  * SC;
        f32x4 a1 = *(const f32x4*)(qp + 32) * SC;
        f32x4 b1 = *(const f32x4*)(qp + 36) * SC;
        qf[rt][0] = cvt8(a0, b0);
        qf[rt][1] = cvt8(a1, b1);
    }

    f32x4 acc[2][4] = {};
    float m[2]  = {-1e30f, -1e30f};
    float lp[2] = {0.f, 0.f};

    const int pb0 = (n0 >= WIN - 1) ? n0 - (WIN - 1) : 0;   // pair base
    const int wlo = nq - (WIN - 1);                          // window low (may be <0)

#define LOADK(KB, RA, RB)                                                         \
    { const int kc_ = ((KB) < NBLK - 1) ? (KB) : (NBLK - 1);                      \
      const float* kp_ = K + base + (size_t)(kc_ * 32 + skrow) * DIM + skc;       \
      RA = *(const f32x4*)kp_;  RB = *(const f32x4*)(kp_ + 4); }
#define LOADV(KB, RA, RB)                                                         \
    { const int kc_ = ((KB) < NBLK - 1) ? (KB) : (NBLK - 1);                      \
      const float* vp_ = V + base + (size_t)(kc_ * 32 + svkey) * DIM + svdg * 4;  \
      RA = *(const f32x4*)vp_;  RB = *(const f32x4*)(vp_ + DIM); }
#define STORE(BUF, SUB, KA, KB_, VA, VB)                                          \
    { *(bf16x8*)&Kt[BUF][SUB][skrow][skc] = cvt8(KA, KB_);                        \
      _Pragma("unroll")                                                           \
      for (int j = 0; j < 4; ++j) {                                               \
          u32 w_ = (u32)__builtin_bit_cast(u16, (__bf16)VA[j])                    \
                 | ((u32)__builtin_bit_cast(u16, (__bf16)VB[j]) << 16);           \
          *(u32*)&Vt[BUF][SUB][svdg * 4 + j][svkey] = w_; } }

    // ---- prologue: stage pair 0 into buf 0 ----
    f32x4 kA0, kA1, kB0, kB1, vA0, vA1, vB0, vB1;
    LOADK(pb0,     kA0, kA1)  LOADK(pb0 + 1, kB0, kB1)
    LOADV(pb0,     vA0, vA1)  LOADV(pb0 + 1, vB0, vB1)
    STORE(0, 0, kA0, kA1, vA0, vA1)
    STORE(0, 1, kB0, kB1, vB0, vB1)
    __syncthreads();

    int cur = 0;
    for (int p = 0; p < 10; ++p) {
        const bool haveNext = (p < 9);
        // ---- issue next pair's loads EARLY ----
        if (haveNext) {
            const int kbn = pb0 + 2 * p + 2;
            LOADK(kbn,     kA0, kA1)  LOADK(kbn + 1, kB0, kB1)
            LOADV(kbn,     vA0, vA1)  LOADV(kbn + 1, vB0, vB1)
        }

        // ---- compute the two sub-blocks (wave-uniform gating) ----
#pragma unroll
        for (int sub = 0; sub < 2; ++sub) {
            const int kb = pb0 + 2 * p + sub;
            if (kb < wlo || kb > nq) continue;   // out of this wave's window

            bf16x8 kf[2][2];
#pragma unroll
            for (int kh = 0; kh < 2; ++kh)
#pragma unroll
                for (int c = 0; c < 2; ++c)
                    kf[kh][c] = *(const bf16x8*)&Kt[cur][sub][kh * 16 + l15][c * 32 + l4 * 8];

            bf16x8 vf[4];
#pragma unroll
            for (int dt = 0; dt < 4; ++dt) {
                bf16x4 lo = *(const bf16x4*)&Vt[cur][sub][dt * 16 + l15][l4 * 4];
                bf16x4 hi = *(const bf16x4*)&Vt[cur][sub][dt * 16 + l15][16 + l4 * 4];
#pragma unroll
                for (int j = 0; j < 4; ++j) { vf[dt][j] = lo[j]; vf[dt][4 + j] = hi[j]; }
            }

            f32x4 s[2][2];
#pragma unroll
            for (int rt = 0; rt < 2; ++rt)
#pragma unroll
                for (int kh = 0; kh < 2; ++kh) {
                    f32x4 a = {};
                    a = __builtin_amdgcn_mfma_f32_16x16x32_bf16(kf[kh][0], qf[rt][0], a, 0, 0, 0);
                    a = __builtin_amdgcn_mfma_f32_16x16x32_bf16(kf[kh][1], qf[rt][1], a, 0, 0, 0);
                    s[rt][kh] = a;
                }

            if (kb == nq) {
#pragma unroll
                for (int rt = 0; rt < 2; ++rt)
#pragma unroll
                    for (int kh = 0; kh < 2; ++kh)
#pragma unroll
                        for (int r = 0; r < 4; ++r)
                            if (kh * 16 + l4 * 4 + r > rt * 16 + l15)
                                s[rt][kh][r] = -1e30f;
            }

            bool ok = true;
#pragma unroll
            for (int rt = 0; rt < 2; ++rt)
#pragma unroll
                for (int kh = 0; kh < 2; ++kh)
#pragma unroll
                    for (int r = 0; r < 4; ++r)
                        ok &= (s[rt][kh][r] <= m[rt] + DTHR);

            if (!__all(ok)) {
#pragma unroll
                for (int rt = 0; rt < 2; ++rt) {
                    float t0 = -1e30f;
#pragma unroll
                    for (int kh = 0; kh < 2; ++kh)
#pragma unroll
                        for (int r = 0; r < 4; ++r) t0 = fmaxf(t0, s[rt][kh][r]);
                    t0 = fmaxf(t0, __shfl_xor(t0, 16));
                    t0 = fmaxf(t0, __shfl_xor(t0, 32));
                    const float mn = fmaxf(m[rt], t0);
                    const float al = exp2f(m[rt] - mn);
                    m[rt] = mn;
                    lp[rt] *= al;
#pragma unroll
                    for (int dt = 0; dt < 4; ++dt)
#pragma unroll
                        for (int r = 0; r < 4; ++r) acc[rt][dt][r] *= al;
                }
            }

            bf16x8 pbf[2];
#pragma unroll
            for (int rt = 0; rt < 2; ++rt) {
                float psum = 0.f;
#pragma unroll
                for (int j = 0; j < 8; ++j) {
                    const float pv = exp2f(s[rt][j >> 2][j & 3] - m[rt]);
                    psum += pv;
                    pbf[rt][j] = (__bf16)pv;
                }
                lp[rt] += psum;
            }

#pragma unroll
            for (int rt = 0; rt < 2; ++rt)
#pragma unroll
                for (int dt = 0; dt < 4; ++dt)
                    acc[rt][dt] = __builtin_amdgcn_mfma_f32_16x16x32_bf16(
                        vf[dt], pbf[rt], acc[rt][dt], 0, 0, 0);
        }

        // ---- write-late: stage next pair into the other buffer ----
        if (haveNext) {
            STORE(cur ^ 1, 0, kA0, kA1, vA0, vA1)
            STORE(cur ^ 1, 1, kB0, kB1, vB0, vB1)
        }

        __syncthreads();
        cur ^= 1;
    }
#undef LOADK
#undef LOADV
#undef STORE

    // ---- epilogue (verified): reduce l, normalize, vector store ----
#pragma unroll
    for (int rt = 0; rt < 2; ++rt) {
        float ps = lp[rt];
        ps += __shfl_xor(ps, 16);
        ps += __shfl_xor(ps, 32);
        const float inv = 1.0f / ps;
        float* op = O + base + (size_t)(nq * 32 + rt * 16 + l15) * DIM + l4 * 4;
#pragma unroll
        for (int dt = 0; dt < 4; ++dt) {
            f32x4 v;
#pragma unroll
            for (int r = 0; r < 4; ++r) v[r] = acc[rt][dt][r] * inv;
            *(f32x4*)(op + dt * 16) = v;
        }
    }
}

extern "C" void kernel_launch(void* const* d_in, const int* in_sizes, int n_in,
                              void* d_out, int out_size, void* d_ws, size_t ws_size,
                              hipStream_t stream)
{
    const float* Q = (const float*)d_in[0];
    const float* K = (const float*)d_in[1];
    const float* V = (const float*)d_in[2];
    float*       O = (float*)d_out;

    const int nwg = 2 * NH * GROUPS;   // 512 WGs x 256 thr
    hipLaunchKernelGGL(sparse_attn_v15, dim3(nwg), dim3(256), 0, stream,
                       Q, K, V, O);
}